// Round 1
// baseline (319.182 us; speedup 1.0000x reference)
//
#include <hip/hip_runtime.h>
#include <hip/hip_bf16.h>

// LSTM cell: B=16384, D=H=1024. out = (h_next, c_next) fp32, each 16384x1024.
// Fused 4-gate bf16-MFMA GEMM: A=[x|h] (16384x2048), per gate Bg=[Wg_x|Wg_h] (1024x2048, K-contig).
// gate = A @ Bg^T + (bg_x+bg_h); epilogue in-register.

#define MROWS 16384
#define NCOLS 1024
#define KTOT  2048

typedef __attribute__((ext_vector_type(8))) short bf16x8;
typedef __attribute__((ext_vector_type(4))) float f32x4;
typedef unsigned int u32;
typedef unsigned short u16;

__device__ __forceinline__ u16 f2bf(float f) {
  union { float f; u32 u; } v; v.f = f;
  u32 r = v.u + 0x7fffu + ((v.u >> 16) & 1u);   // RNE truncate f32->bf16
  return (u16)(r >> 16);
}

__device__ __forceinline__ bf16x8 pack8(float4 lo, float4 hi) {
  bf16x8 v;
  v[0] = (short)f2bf(lo.x); v[1] = (short)f2bf(lo.y);
  v[2] = (short)f2bf(lo.z); v[3] = (short)f2bf(lo.w);
  v[4] = (short)f2bf(hi.x); v[5] = (short)f2bf(hi.y);
  v[6] = (short)f2bf(hi.z); v[7] = (short)f2bf(hi.w);
  return v;
}

__device__ __forceinline__ float tanh_fast(float x) {
  float e = __expf(2.0f * x);
  return 1.0f - 2.0f / (e + 1.0f);
}

typedef __attribute__((address_space(1))) const u32 gas_u32;
typedef __attribute__((address_space(3))) u32 las_u32;

__device__ __forceinline__ void gl_lds16(const void* g, void* l) {
  __builtin_amdgcn_global_load_lds((gas_u32*)g, (las_u32*)l, 16, 0, 0);
}

// ---- conversion kernels (fast path, need ws >= 80MB) ----
// A_bf16: [16384][2048] bf16; cols 0..1023 = x, 1024..2047 = h.
__global__ void __launch_bounds__(256) convA(const float* __restrict__ x,
                                             const float* __restrict__ h,
                                             u16* __restrict__ A) {
  u32 t = blockIdx.x * 256u + threadIdx.x;          // 4096 blocks -> 1048576 threads
  #pragma unroll
  for (int i = 0; i < 4; ++i) {
    u32 chunk = t + (u32)i * 1048576u;              // 8 elems per chunk, 4194304 chunks
    u32 row = chunk >> 8;                           // 256 chunks per row
    u32 cpos = (chunk & 255u) * 8u;
    const float* src = (cpos < 1024u) ? (x + (size_t)row * 1024 + cpos)
                                      : (h + (size_t)row * 1024 + (cpos - 1024u));
    float4 lo = *(const float4*)src;
    float4 hi = *(const float4*)(src + 4);
    *(bf16x8*)(A + (size_t)chunk * 8) = pack8(lo, hi);
  }
}

// W_bf16: [gate][1024][2048] bf16, gate order i,f,c,o; k 0..1023 = W*_x, 1024..2047 = W*_h.
__global__ void __launch_bounds__(256) convW(const float* __restrict__ wix, const float* __restrict__ wfx,
                                             const float* __restrict__ wcx, const float* __restrict__ wox,
                                             const float* __restrict__ wih, const float* __restrict__ wfh,
                                             const float* __restrict__ wch, const float* __restrict__ woh,
                                             u16* __restrict__ W) {
  u32 t = blockIdx.x * 256u + threadIdx.x;          // 1024 blocks -> 262144 threads
  const float* WX[4] = {wix, wfx, wcx, wox};
  const float* WH[4] = {wih, wfh, wch, woh};
  #pragma unroll
  for (int g = 0; g < 4; ++g) {
    u32 c3 = t;                                     // chunk within gate, 0..262143
    u32 n = c3 >> 8;
    u32 cpos = (c3 & 255u) * 8u;
    const float* src = (cpos < 1024u) ? (WX[g] + (size_t)n * 1024 + cpos)
                                      : (WH[g] + (size_t)n * 1024 + (cpos - 1024u));
    float4 lo = *(const float4*)src;
    float4 hi = *(const float4*)(src + 4);
    *(bf16x8*)(W + (size_t)g * 2097152 + (size_t)c3 * 8) = pack8(lo, hi);
  }
}

// ---- fused 4-gate GEMM + LSTM epilogue ----
// Block: 256 thr (4 waves, 2x2). Tile 128(M) x 64(N per gate), BK=64.
// Wave: 64x32 per gate -> acc[4 gates][4 m][2 n] f32x4 = 128 regs.
// LDS: sA[128][64] + sB[4][64][64] bf16, XOR-swizzled rows (byte ^= (row&7)<<4).
template <bool FAST>
__global__ void __launch_bounds__(256, 2) lstm_gemm(
    const u16* __restrict__ Abf, const u16* __restrict__ Wbf,
    const float* __restrict__ x, const float* __restrict__ h,
    const float* __restrict__ wix, const float* __restrict__ wfx,
    const float* __restrict__ wcx, const float* __restrict__ wox,
    const float* __restrict__ wih, const float* __restrict__ wfh,
    const float* __restrict__ wch, const float* __restrict__ woh,
    const float* __restrict__ bix, const float* __restrict__ bfx,
    const float* __restrict__ bcx, const float* __restrict__ box_,
    const float* __restrict__ bih, const float* __restrict__ bfh,
    const float* __restrict__ bch, const float* __restrict__ boh,
    const float* __restrict__ cprev, float* __restrict__ out) {
  __shared__ alignas(16) u16 sA[128 * 64];       // 16 KB
  __shared__ alignas(16) u16 sB[4 * 64 * 64];    // 32 KB

  const u32 tid = threadIdx.x;
  const u32 lane = tid & 63u;
  const u32 wid = tid >> 6;
  const u32 wr = wid >> 1, wc = wid & 1u;
  const u32 bidx = blockIdx.x;
  const u32 bm = bidx >> 4, bn = bidx & 15u;     // 128 x 16 tiles

  f32x4 acc[4][4][2];
  #pragma unroll
  for (int g = 0; g < 4; ++g)
    #pragma unroll
    for (int m = 0; m < 4; ++m)
      #pragma unroll
      for (int n = 0; n < 2; ++n)
        acc[g][m][n] = (f32x4){0.f, 0.f, 0.f, 0.f};

  const u32 l15 = lane & 15u, l4 = lane >> 4;

  for (int kt = 0; kt < KTOT / 64; ++kt) {
    const u32 k0 = (u32)kt * 64u;
    if (kt) __syncthreads();

    if constexpr (FAST) {
      // A tile: 1024 chunks of 16B; linear LDS dest, inverse-swizzled global src.
      #pragma unroll
      for (int j = 0; j < 4; ++j) {
        u32 chunk = (wid * 4u + j) * 64u + lane;
        u32 row = chunk >> 3;
        u32 cole = ((chunk & 7u) * 8u) ^ ((row & 7u) << 3);
        const u16* g = Abf + (size_t)(bm * 128u + row) * KTOT + k0 + cole;
        gl_lds16((const void*)g, (void*)(sA + (wid * 4u + j) * 512u));
      }
      // B tiles: 2048 chunks.
      #pragma unroll
      for (int j = 0; j < 8; ++j) {
        u32 chunk = (wid * 8u + j) * 64u + lane;
        u32 gate = chunk >> 9;
        u32 c3 = chunk & 511u;
        u32 row = c3 >> 3;
        u32 cole = ((c3 & 7u) * 8u) ^ ((row & 7u) << 3);
        const u16* g = Wbf + (size_t)gate * 2097152 + (size_t)(bn * 64u + row) * KTOT + k0 + cole;
        gl_lds16((const void*)g, (void*)(sB + (wid * 8u + j) * 512u));
      }
    } else {
      // Fallback: reg-stage fp32 -> bf16, swizzled ds_write.
      #pragma unroll
      for (int c = 0; c < 4; ++c) {
        u32 chunk = tid + (u32)c * 256u;
        u32 row = chunk >> 3;
        u32 cp = (chunk & 7u) * 8u;
        u32 gk = k0 + cp;
        const float* src = (gk < 1024u) ? (x + (size_t)(bm * 128u + row) * 1024 + gk)
                                        : (h + (size_t)(bm * 128u + row) * 1024 + (gk - 1024u));
        float4 lo = *(const float4*)src;
        float4 hi = *(const float4*)(src + 4);
        u32 dst = row * 128u + ((cp * 2u) ^ ((row & 7u) << 4));
        *(bf16x8*)((char*)sA + dst) = pack8(lo, hi);
      }
      #pragma unroll
      for (int g = 0; g < 4; ++g) {
        const float* Wxg = (g == 0) ? wix : (g == 1) ? wfx : (g == 2) ? wcx : wox;
        const float* Whg = (g == 0) ? wih : (g == 1) ? wfh : (g == 2) ? wch : woh;
        #pragma unroll
        for (int cc = 0; cc < 2; ++cc) {
          u32 c3 = tid + (u32)cc * 256u;
          u32 row = c3 >> 3;
          u32 cp = (c3 & 7u) * 8u;
          u32 gk = k0 + cp;
          const float* src = (gk < 1024u) ? (Wxg + (size_t)(bn * 64u + row) * 1024 + gk)
                                          : (Whg + (size_t)(bn * 64u + row) * 1024 + (gk - 1024u));
          float4 lo = *(const float4*)src;
          float4 hi = *(const float4*)(src + 4);
          u32 dst = (u32)g * 8192u + row * 128u + ((cp * 2u) ^ ((row & 7u) << 4));
          *(bf16x8*)((char*)sB + dst) = pack8(lo, hi);
        }
      }
    }
    __syncthreads();

    #pragma unroll
    for (int s = 0; s < 2; ++s) {
      bf16x8 af[4];
      #pragma unroll
      for (int m = 0; m < 4; ++m) {
        u32 mrow = wr * 64u + (u32)m * 16u + l15;
        u32 off = mrow * 128u + (((u32)s * 64u + l4 * 16u) ^ ((mrow & 7u) << 4));
        af[m] = *(const bf16x8*)((const char*)sA + off);
      }
      #pragma unroll
      for (int g = 0; g < 4; ++g) {
        #pragma unroll
        for (int nf = 0; nf < 2; ++nf) {
          u32 nrow = wc * 32u + (u32)nf * 16u + l15;
          u32 off = (u32)g * 8192u + nrow * 128u +
                    (((u32)s * 64u + l4 * 16u) ^ ((nrow & 7u) << 4));
          bf16x8 bfr = *(const bf16x8*)((const char*)sB + off);
          #pragma unroll
          for (int m = 0; m < 4; ++m)
            acc[g][m][nf] = __builtin_amdgcn_mfma_f32_16x16x32_bf16(af[m], bfr, acc[g][m][nf], 0, 0, 0);
        }
      }
    }
  }

  // ---- epilogue: gates -> (h_next, c_next) ----
  #pragma unroll
  for (int nf = 0; nf < 2; ++nf) {
    u32 col = bn * 64u + wc * 32u + (u32)nf * 16u + l15;
    float bi = bix[col] + bih[col];
    float bff = bfx[col] + bfh[col];
    float bc = bcx[col] + bch[col];
    float bo = box_[col] + boh[col];
    #pragma unroll
    for (int m = 0; m < 4; ++m) {
      u32 row0 = bm * 128u + wr * 64u + (u32)m * 16u + l4 * 4u;
      #pragma unroll
      for (int r = 0; r < 4; ++r) {
        size_t idx = (size_t)(row0 + (u32)r) * 1024 + col;
        float iv = acc[0][m][nf][r] + bi;
        float fv = acc[1][m][nf][r] + bff;
        float gv = tanh_fast(acc[2][m][nf][r] + bc);
        float ov = acc[3][m][nf][r] + bo;
        float cp = cprev[idx];
        float cn = gv * iv + cp * fv;
        out[idx] = ov * tanh_fast(cn);
        out[(size_t)16777216 + idx] = cn;
      }
    }
  }
}

extern "C" void kernel_launch(void* const* d_in, const int* in_sizes, int n_in,
                              void* d_out, int out_size, void* d_ws, size_t ws_size,
                              hipStream_t stream) {
  const float* x = (const float*)d_in[0];
  const float* h = (const float*)d_in[1];
  const float* cprev = (const float*)d_in[2];
  const float* wix = (const float*)d_in[3];  const float* bix = (const float*)d_in[4];
  const float* wfx = (const float*)d_in[5];  const float* bfx = (const float*)d_in[6];
  const float* wcx = (const float*)d_in[7];  const float* bcx = (const float*)d_in[8];
  const float* wox = (const float*)d_in[9];  const float* box_ = (const float*)d_in[10];
  const float* wih = (const float*)d_in[11]; const float* bih = (const float*)d_in[12];
  const float* wfh = (const float*)d_in[13]; const float* bfh = (const float*)d_in[14];
  const float* wch = (const float*)d_in[15]; const float* bch = (const float*)d_in[16];
  const float* woh = (const float*)d_in[17]; const float* boh = (const float*)d_in[18];
  float* out = (float*)d_out;

  const size_t needA = (size_t)MROWS * KTOT * 2;       // 67,108,864 B
  const size_t needW = (size_t)4 * NCOLS * KTOT * 2;   // 16,777,216 B

  if (ws_size >= needA + needW) {
    u16* Abf = (u16*)d_ws;
    u16* Wbf = (u16*)((char*)d_ws + needA);
    convA<<<dim3(4096), dim3(256), 0, stream>>>(x, h, Abf);
    convW<<<dim3(1024), dim3(256), 0, stream>>>(wix, wfx, wcx, wox, wih, wfh, wch, woh, Wbf);
    lstm_gemm<true><<<dim3(2048), dim3(256), 0, stream>>>(
        Abf, Wbf, nullptr, nullptr,
        nullptr, nullptr, nullptr, nullptr, nullptr, nullptr, nullptr, nullptr,
        bix, bfx, bcx, box_, bih, bfh, bch, boh, cprev, out);
  } else {
    lstm_gemm<false><<<dim3(2048), dim3(256), 0, stream>>>(
        nullptr, nullptr, x, h,
        wix, wfx, wcx, wox, wih, wfh, wch, woh,
        bix, bfx, bcx, box_, bih, bfh, bch, boh, cprev, out);
  }
}